// Round 1
// baseline (135.312 us; speedup 1.0000x reference)
//
#include <hip/hip_runtime.h>
#include <math.h>

#define BB 8
#define HH 256
#define WW 256
#define NPIX (BB*HH*WW)   // 524288

// ---------------------------------------------------------------------------
// Kernel 1: per-column vertical EDT pass (both polarities).
// gA = running distance to nearest bg (~fg) pixel in column (feature = !fg)
// gB = running distance to nearest fg pixel in column   (feature = fg)
// Forward pass stores raw forward distances; backward pass combines
// (min with backward running distance), caps at big=H+W, squares in place.
// ---------------------------------------------------------------------------
__global__ __launch_bounds__(64) void edt_vertical(
    const float* __restrict__ tgt,
    float* __restrict__ gA2,
    float* __restrict__ gB2) {
  int col = blockIdx.x * blockDim.x + threadIdx.x;  // 0 .. B*W-1
  if (col >= BB * WW) return;
  int b = col / WW;
  int w = col % WW;
  const float* tcol = tgt + (size_t)b * HH * WW + w;
  float* Acol = gA2 + (size_t)b * HH * WW + w;
  float* Bcol = gB2 + (size_t)b * HH * WW + w;
  const float big = (float)(HH + WW);  // 512

  float dA = big, dB = big;
#pragma unroll 4
  for (int h = 0; h < HH; ++h) {
    float t = tcol[h * WW];
    bool fg = t > 0.5f;
    dA = fg ? dA + 1.0f : 0.0f;   // feature for A-EDT is bg pixel
    dB = fg ? 0.0f : dB + 1.0f;   // feature for B-EDT is fg pixel
    Acol[h * WW] = dA;
    Bcol[h * WW] = dB;
  }
  dA = big;
  dB = big;
#pragma unroll 4
  for (int h = HH - 1; h >= 0; --h) {
    float fA = Acol[h * WW];
    float fB = Bcol[h * WW];
    // forward value is exactly 0 iff this pixel is the feature of that EDT
    dA = (fA == 0.0f) ? 0.0f : dA + 1.0f;
    dB = (fB == 0.0f) ? 0.0f : dB + 1.0f;
    float gA = fminf(fminf(fA, dA), big);
    float gB = fminf(fminf(fB, dB), big);
    Acol[h * WW] = gA * gA;
    Bcol[h * WW] = gB * gB;
  }
}

// ---------------------------------------------------------------------------
// Kernel 2: per-row dense lower envelope + fused loss + reduction.
// One block (256 threads) per (b,h) row. Each thread owns one output column,
// scans the selected g2 row (A if fg else B) held in LDS.
// ---------------------------------------------------------------------------
__global__ __launch_bounds__(256) void edt_row_loss(
    const float* __restrict__ pred,
    const float* __restrict__ tgt,
    const float* __restrict__ gA2,
    const float* __restrict__ gB2,
    float* __restrict__ out) {
  __shared__ float lA[WW];
  __shared__ float lB[WW];
  __shared__ float wsum[4];

  int w = threadIdx.x;
  size_t base = (size_t)blockIdx.x * WW;  // blockIdx.x enumerates b*H+h

  lA[w] = gA2[base + w];
  lB[w] = gB2[base + w];
  __syncthreads();

  float x = pred[base + w];
  float t = tgt[base + w];
  bool fg = t > 0.5f;
  const float* sel = fg ? lA : lB;

  float d2 = 3.4e38f;
  float delta = (float)w;  // w - j, decremented each iteration
#pragma unroll 8
  for (int j = 0; j < WW; ++j) {
    d2 = fminf(d2, fmaf(delta, delta, sel[j]));
    delta -= 1.0f;
  }

  float d = sqrtf(d2);
  // weight = sigmoid(-(d - THETA0)/THETA) = 1/(1+exp((d-3)/5))
  float weight = 1.0f / (1.0f + __expf((d - 3.0f) * 0.2f));
  // stable BCE with logits
  float bce = fmaxf(x, 0.0f) - x * t + log1pf(__expf(-fabsf(x)));
  float c = bce * weight * (1.0f / (float)NPIX);

  // wave reduction (64 lanes)
#pragma unroll
  for (int off = 32; off > 0; off >>= 1) c += __shfl_down(c, off, 64);
  if ((threadIdx.x & 63) == 0) wsum[threadIdx.x >> 6] = c;
  __syncthreads();
  if (threadIdx.x == 0) {
    atomicAdd(out, wsum[0] + wsum[1] + wsum[2] + wsum[3]);
  }
}

extern "C" void kernel_launch(void* const* d_in, const int* in_sizes, int n_in,
                              void* d_out, int out_size, void* d_ws, size_t ws_size,
                              hipStream_t stream) {
  const float* pred = (const float*)d_in[0];
  const float* tgt  = (const float*)d_in[1];
  float* out = (float*)d_out;
  float* gA2 = (float*)d_ws;
  float* gB2 = gA2 + NPIX;

  // d_out is poisoned before every timed call — zero the accumulator.
  hipMemsetAsync(d_out, 0, sizeof(float), stream);

  edt_vertical<<<dim3((BB * WW + 63) / 64), dim3(64), 0, stream>>>(tgt, gA2, gB2);
  edt_row_loss<<<dim3(BB * HH), dim3(256), 0, stream>>>(pred, tgt, gA2, gB2, out);
}

// Round 2
// 97.479 us; speedup vs baseline: 1.3881x; 1.3881x over previous
//
#include <hip/hip_runtime.h>
#include <math.h>

#define BB 8
#define HH 256
#define WW 256
#define NPIX (BB*HH*WW)   // 524288
#define BIGF 512.0f       // H + W, the reference cap
#define INF9 1e9f

// ---------------------------------------------------------------------------
// Kernel 1: vertical EDT via wave-parallel min-plus scan.
// One wave per column (2048 waves total). Lane l owns rows 4l..4l+3.
// Forward/backward nearest-feature distances via Hillis-Steele doubling with
// the min-plus operator: jumping s lanes adds 4s rows of distance.
// Computes both polarities (A: feature = !fg, B: feature = fg), stores g^2.
// ---------------------------------------------------------------------------
__device__ __forceinline__ void col_scan_g2(bool f0, bool f1, bool f2, bool f3,
                                            int lane, float g2[4]) {
  // local forward distances within this lane's 4-row segment
  float d = INF9;
  d = f0 ? 0.0f : d + 1.0f; float lf0 = d;
  d = f1 ? 0.0f : d + 1.0f; float lf1 = d;
  d = f2 ? 0.0f : d + 1.0f; float lf2 = d;
  d = f3 ? 0.0f : d + 1.0f; float lf3 = d;
  // inclusive min-plus scan over lanes (distance at h = 4*lane+3)
  float F = lf3;
#pragma unroll
  for (int s = 1; s < 64; s <<= 1) {
    float u = __shfl_up(F, s, 64) + 4.0f * (float)s;
    if (lane >= s) F = fminf(F, u);
  }
  float Fe = __shfl_up(F, 1, 64);   // distance at h = 4*lane-1
  if (lane == 0) Fe = INF9;

  // local backward distances
  d = INF9;
  d = f3 ? 0.0f : d + 1.0f; float lb3 = d;
  d = f2 ? 0.0f : d + 1.0f; float lb2 = d;
  d = f1 ? 0.0f : d + 1.0f; float lb1 = d;
  d = f0 ? 0.0f : d + 1.0f; float lb0 = d;
  float Bv = lb0;                   // distance at h = 4*lane (looking down)
#pragma unroll
  for (int s = 1; s < 64; s <<= 1) {
    float u = __shfl_down(Bv, s, 64) + 4.0f * (float)s;
    if (lane < 64 - s) Bv = fminf(Bv, u);
  }
  float Be = __shfl_down(Bv, 1, 64);  // distance at h = 4*lane+4
  if (lane == 63) Be = INF9;

  float v0 = fminf(fminf(lf0, Fe + 1.0f), fminf(lb0, Be + 4.0f));
  float v1 = fminf(fminf(lf1, Fe + 2.0f), fminf(lb1, Be + 3.0f));
  float v2 = fminf(fminf(lf2, Fe + 3.0f), fminf(lb2, Be + 2.0f));
  float v3 = fminf(fminf(lf3, Fe + 4.0f), fminf(lb3, Be + 1.0f));
  v0 = fminf(v0, BIGF); v1 = fminf(v1, BIGF);
  v2 = fminf(v2, BIGF); v3 = fminf(v3, BIGF);
  g2[0] = v0 * v0; g2[1] = v1 * v1; g2[2] = v2 * v2; g2[3] = v3 * v3;
}

__global__ __launch_bounds__(256) void edt_vertical2(
    const float* __restrict__ tgt,
    float* __restrict__ gA2,
    float* __restrict__ gB2,
    float* __restrict__ out) {
  // zero the loss accumulator (replaces a memset dispatch; K2 runs after us)
  if (blockIdx.x == 0 && threadIdx.x == 0) out[0] = 0.0f;

  int wid = (blockIdx.x * 256 + threadIdx.x) >> 6;  // 0..2047 column id
  int lane = threadIdx.x & 63;
  int b = wid >> 8;
  int w = wid & 255;
  size_t ibase = (size_t)b * HH * WW + w;

  float t0 = tgt[ibase + (size_t)(4 * lane + 0) * WW];
  float t1 = tgt[ibase + (size_t)(4 * lane + 1) * WW];
  float t2 = tgt[ibase + (size_t)(4 * lane + 2) * WW];
  float t3 = tgt[ibase + (size_t)(4 * lane + 3) * WW];
  bool g0 = t0 > 0.5f, g1 = t1 > 0.5f, g2b = t2 > 0.5f, g3 = t3 > 0.5f;

  float a2[4], b2[4];
  col_scan_g2(!g0, !g1, !g2b, !g3, lane, a2);  // A: feature = bg
  col_scan_g2(g0, g1, g2b, g3, lane, b2);      // B: feature = fg

#pragma unroll
  for (int k = 0; k < 4; ++k) {
    size_t o = ibase + (size_t)(4 * lane + k) * WW;
    gA2[o] = a2[k];
    gB2[o] = b2[k];
  }
}

// ---------------------------------------------------------------------------
// Kernel 2: per-row dense lower envelope (windowed to |w-j| <= 64) + fused
// loss + reduction. One block per (b,h) row; float4 LDS reads (b128).
// Window safety: if true d <= 64 the argmin satisfies |w-j| <= d <= 64, so the
// result is exact; if d > 64 both exact and windowed weights are < 5e-6.
// ---------------------------------------------------------------------------
__global__ __launch_bounds__(256) void edt_row_loss2(
    const float* __restrict__ pred,
    const float* __restrict__ tgt,
    const float* __restrict__ gA2,
    const float* __restrict__ gB2,
    float* __restrict__ out) {
  __shared__ __align__(16) float lA[WW];
  __shared__ __align__(16) float lB[WW];
  __shared__ float wsum[4];

  int w = threadIdx.x;
  size_t base = (size_t)blockIdx.x * WW;

  lA[w] = gA2[base + w];
  lB[w] = gB2[base + w];
  float x = pred[base + w];
  float t = tgt[base + w];
  __syncthreads();

  bool fg = t > 0.5f;
  const float4* s4 = (const float4*)(fg ? lA : lB);

  // wave-uniform union window over j-groups of 4
  int w0 = w & ~63;
  int k0 = max(0, w0 - 64) >> 2;
  int k1 = min(WW - 1, w0 + 127) >> 2;

  float D0 = (float)(w - 4 * k0);
  float D1 = D0 - 1.0f, D2 = D0 - 2.0f, D3 = D0 - 3.0f;
  float d2 = 1e30f;
#pragma unroll 4
  for (int k = k0; k <= k1; ++k) {
    float4 v = s4[k];
    d2 = fminf(d2, fmaf(D0, D0, v.x));
    d2 = fminf(d2, fmaf(D1, D1, v.y));
    d2 = fminf(d2, fmaf(D2, D2, v.z));
    d2 = fminf(d2, fmaf(D3, D3, v.w));
    D0 -= 4.0f; D1 -= 4.0f; D2 -= 4.0f; D3 -= 4.0f;
  }

  float dd = sqrtf(d2);
  float weight = 1.0f / (1.0f + __expf((dd - 3.0f) * 0.2f));
  float bce = fmaxf(x, 0.0f) - x * t + log1pf(__expf(-fabsf(x)));
  float c = bce * weight * (1.0f / (float)NPIX);

#pragma unroll
  for (int off = 32; off > 0; off >>= 1) c += __shfl_down(c, off, 64);
  if ((threadIdx.x & 63) == 0) wsum[threadIdx.x >> 6] = c;
  __syncthreads();
  if (threadIdx.x == 0) {
    atomicAdd(out, wsum[0] + wsum[1] + wsum[2] + wsum[3]);
  }
}

extern "C" void kernel_launch(void* const* d_in, const int* in_sizes, int n_in,
                              void* d_out, int out_size, void* d_ws, size_t ws_size,
                              hipStream_t stream) {
  const float* pred = (const float*)d_in[0];
  const float* tgt  = (const float*)d_in[1];
  float* out = (float*)d_out;
  float* gA2 = (float*)d_ws;
  float* gB2 = gA2 + NPIX;

  edt_vertical2<<<dim3(2048 / 4), dim3(256), 0, stream>>>(tgt, gA2, gB2, out);
  edt_row_loss2<<<dim3(BB * HH), dim3(256), 0, stream>>>(pred, tgt, gA2, gB2, out);
}

// Round 3
// 83.308 us; speedup vs baseline: 1.6242x; 1.1701x over previous
//
#include <hip/hip_runtime.h>
#include <math.h>

#define BB 8
#define HH 256
#define WW 256
#define NPIX (BB*HH*WW)   // 524288
#define BIGF 512.0f       // H + W, the reference cap
#define INF9 1e9f

// ws layout (floats): gA2 [0,524288) | gB2 [524288,1048576) |
//                     partials: 16 slots, stride 32 floats (128 B) | counter (int)
#define P_OFF   (2 * NPIX)
#define P_STRIDE 32
#define C_OFF   (P_OFF + 16 * P_STRIDE)

// ---------------------------------------------------------------------------
// Kernel 1: vertical EDT via wave-parallel min-plus scan (one wave/column).
// Lane l owns rows 4l..4l+3; Hillis-Steele min-plus doubling over lanes.
// Also zeroes the reduction partials + counter for kernel 2.
// ---------------------------------------------------------------------------
__device__ __forceinline__ void col_scan_g2(bool f0, bool f1, bool f2, bool f3,
                                            int lane, float g2[4]) {
  float d = INF9;
  d = f0 ? 0.0f : d + 1.0f; float lf0 = d;
  d = f1 ? 0.0f : d + 1.0f; float lf1 = d;
  d = f2 ? 0.0f : d + 1.0f; float lf2 = d;
  d = f3 ? 0.0f : d + 1.0f; float lf3 = d;
  float F = lf3;
#pragma unroll
  for (int s = 1; s < 64; s <<= 1) {
    float u = __shfl_up(F, s, 64) + 4.0f * (float)s;
    if (lane >= s) F = fminf(F, u);
  }
  float Fe = __shfl_up(F, 1, 64);
  if (lane == 0) Fe = INF9;

  d = INF9;
  d = f3 ? 0.0f : d + 1.0f; float lb3 = d;
  d = f2 ? 0.0f : d + 1.0f; float lb2 = d;
  d = f1 ? 0.0f : d + 1.0f; float lb1 = d;
  d = f0 ? 0.0f : d + 1.0f; float lb0 = d;
  float Bv = lb0;
#pragma unroll
  for (int s = 1; s < 64; s <<= 1) {
    float u = __shfl_down(Bv, s, 64) + 4.0f * (float)s;
    if (lane < 64 - s) Bv = fminf(Bv, u);
  }
  float Be = __shfl_down(Bv, 1, 64);
  if (lane == 63) Be = INF9;

  float v0 = fminf(fminf(lf0, Fe + 1.0f), fminf(lb0, Be + 4.0f));
  float v1 = fminf(fminf(lf1, Fe + 2.0f), fminf(lb1, Be + 3.0f));
  float v2 = fminf(fminf(lf2, Fe + 3.0f), fminf(lb2, Be + 2.0f));
  float v3 = fminf(fminf(lf3, Fe + 4.0f), fminf(lb3, Be + 1.0f));
  v0 = fminf(v0, BIGF); v1 = fminf(v1, BIGF);
  v2 = fminf(v2, BIGF); v3 = fminf(v3, BIGF);
  g2[0] = v0 * v0; g2[1] = v1 * v1; g2[2] = v2 * v2; g2[3] = v3 * v3;
}

__global__ __launch_bounds__(256) void edt_vertical2(
    const float* __restrict__ tgt,
    float* __restrict__ ws) {
  if (blockIdx.x == 0) {
    if (threadIdx.x < 16) ws[P_OFF + threadIdx.x * P_STRIDE] = 0.0f;
    if (threadIdx.x == 16) ((int*)ws)[C_OFF] = 0;
  }

  float* gA2 = ws;
  float* gB2 = ws + NPIX;

  int wid = (blockIdx.x * 256 + threadIdx.x) >> 6;  // column id 0..2047
  int lane = threadIdx.x & 63;
  int b = wid >> 8;
  int w = wid & 255;
  size_t ibase = (size_t)b * HH * WW + w;

  float t0 = tgt[ibase + (size_t)(4 * lane + 0) * WW];
  float t1 = tgt[ibase + (size_t)(4 * lane + 1) * WW];
  float t2 = tgt[ibase + (size_t)(4 * lane + 2) * WW];
  float t3 = tgt[ibase + (size_t)(4 * lane + 3) * WW];
  bool g0 = t0 > 0.5f, g1 = t1 > 0.5f, g2b = t2 > 0.5f, g3 = t3 > 0.5f;

  float a2[4], b2[4];
  col_scan_g2(!g0, !g1, !g2b, !g3, lane, a2);  // A: feature = bg
  col_scan_g2(g0, g1, g2b, g3, lane, b2);      // B: feature = fg

#pragma unroll
  for (int k = 0; k < 4; ++k) {
    size_t o = ibase + (size_t)(4 * lane + k) * WW;
    gA2[o] = a2[k];
    gB2[o] = b2[k];
  }
}

// ---------------------------------------------------------------------------
// Kernel 2: 4 rows per block (1024 threads, 16 waves). Windowed lower
// envelope (|w-j| <= 64, exact where it matters; weight < 5e-6 beyond) +
// fused loss. Reduction: wave shuffle -> LDS -> ONE atomicAdd per block to
// 16 spread partial slots; last block (atomic counter) sums the 16 partials
// and writes out[0] directly.
// ---------------------------------------------------------------------------
__global__ __launch_bounds__(1024) void edt_row_loss3(
    const float* __restrict__ pred,
    const float* __restrict__ tgt,
    float* __restrict__ ws,
    float* __restrict__ out) {
  __shared__ __align__(16) float lA[4][WW];
  __shared__ __align__(16) float lB[4][WW];
  __shared__ float wsum[16];
  __shared__ int lastFlag;

  const float* gA2 = ws;
  const float* gB2 = ws + NPIX;
  float* partials = ws + P_OFF;
  int* counter = ((int*)ws) + C_OFF;

  int tid = threadIdx.x;
  size_t base = (size_t)blockIdx.x * (4 * WW);

  ((float*)lA)[tid] = gA2[base + tid];
  ((float*)lB)[tid] = gB2[base + tid];
  float x = pred[base + tid];
  float t = tgt[base + tid];
  __syncthreads();

  int r = tid >> 8;    // row within block
  int w = tid & 255;   // column
  bool fg = t > 0.5f;
  const float4* s4 = (const float4*)(fg ? lA[r] : lB[r]);

  // wave-uniform union window over j-groups of 4 (64 threads share w0)
  int w0 = w & ~63;
  int k0 = max(0, w0 - 64) >> 2;
  int k1 = min(WW - 1, w0 + 127) >> 2;

  float D0 = (float)(w - 4 * k0);
  float D1 = D0 - 1.0f, D2 = D0 - 2.0f, D3 = D0 - 3.0f;
  float d2 = 1e30f;
#pragma unroll 4
  for (int k = k0; k <= k1; ++k) {
    float4 v = s4[k];
    d2 = fminf(d2, fmaf(D0, D0, v.x));
    d2 = fminf(d2, fmaf(D1, D1, v.y));
    d2 = fminf(d2, fmaf(D2, D2, v.z));
    d2 = fminf(d2, fmaf(D3, D3, v.w));
    D0 -= 4.0f; D1 -= 4.0f; D2 -= 4.0f; D3 -= 4.0f;
  }

  float dd = sqrtf(d2);
  float weight = 1.0f / (1.0f + __expf((dd - 3.0f) * 0.2f));
  float bce = fmaxf(x, 0.0f) - x * t + log1pf(__expf(-fabsf(x)));
  float c = bce * weight * (1.0f / (float)NPIX);

  // wave reduction (64 lanes) -> 16 partials in LDS
#pragma unroll
  for (int off = 32; off > 0; off >>= 1) c += __shfl_down(c, off, 64);
  if ((tid & 63) == 0) wsum[tid >> 6] = c;
  __syncthreads();

  // first wave reduces the 16 values; one spread atomic per block
  if (tid < 64) {
    float v = (tid < 16) ? wsum[tid] : 0.0f;
#pragma unroll
    for (int off = 8; off > 0; off >>= 1) v += __shfl_down(v, off, 64);
    if (tid == 0) {
      atomicAdd(&partials[(blockIdx.x & 15) * P_STRIDE], v);
      __threadfence();
      int done = atomicAdd(counter, 1);
      lastFlag = (done == (int)gridDim.x - 1) ? 1 : 0;
    }
  }
  __syncthreads();

  if (lastFlag && tid < 64) {
    // coherent reads of the partials (atomic 0-add bypasses stale L1)
    float v = (tid < 16) ? atomicAdd(&partials[tid * P_STRIDE], 0.0f) : 0.0f;
#pragma unroll
    for (int off = 8; off > 0; off >>= 1) v += __shfl_down(v, off, 64);
    if (tid == 0) out[0] = v;
  }
}

extern "C" void kernel_launch(void* const* d_in, const int* in_sizes, int n_in,
                              void* d_out, int out_size, void* d_ws, size_t ws_size,
                              hipStream_t stream) {
  const float* pred = (const float*)d_in[0];
  const float* tgt  = (const float*)d_in[1];
  float* out = (float*)d_out;
  float* ws  = (float*)d_ws;

  edt_vertical2<<<dim3(512), dim3(256), 0, stream>>>(tgt, ws);
  edt_row_loss3<<<dim3(512), dim3(1024), 0, stream>>>(pred, tgt, ws, out);
}

// Round 4
// 80.133 us; speedup vs baseline: 1.6886x; 1.0396x over previous
//
#include <hip/hip_runtime.h>
#include <math.h>

#define BB 8
#define HH 256
#define WW 256
#define NPIX (BB*HH*WW)   // 524288
#define BIGF 512.0f       // H + W, the reference cap
#define INF9 1e9f

// ws layout (floats): gA2 [0,524288) | gB2 [524288,1048576) |
//                     partials: 16 slots, stride 32 floats (128 B) | counter (int)
#define P_OFF   (2 * NPIX)
#define P_STRIDE 32
#define C_OFF   (P_OFF + 16 * P_STRIDE)

// ---------------------------------------------------------------------------
// Kernel 1: vertical EDT via wave-parallel min-plus scan (one wave/column).
// Lane l owns rows 4l..4l+3; Hillis-Steele min-plus doubling over lanes.
// Also zeroes the reduction partials + counter for kernel 2.
// ---------------------------------------------------------------------------
__device__ __forceinline__ void col_scan_g2(bool f0, bool f1, bool f2, bool f3,
                                            int lane, float g2[4]) {
  float d = INF9;
  d = f0 ? 0.0f : d + 1.0f; float lf0 = d;
  d = f1 ? 0.0f : d + 1.0f; float lf1 = d;
  d = f2 ? 0.0f : d + 1.0f; float lf2 = d;
  d = f3 ? 0.0f : d + 1.0f; float lf3 = d;
  float F = lf3;
#pragma unroll
  for (int s = 1; s < 64; s <<= 1) {
    float u = __shfl_up(F, s, 64) + 4.0f * (float)s;
    if (lane >= s) F = fminf(F, u);
  }
  float Fe = __shfl_up(F, 1, 64);
  if (lane == 0) Fe = INF9;

  d = INF9;
  d = f3 ? 0.0f : d + 1.0f; float lb3 = d;
  d = f2 ? 0.0f : d + 1.0f; float lb2 = d;
  d = f1 ? 0.0f : d + 1.0f; float lb1 = d;
  d = f0 ? 0.0f : d + 1.0f; float lb0 = d;
  float Bv = lb0;
#pragma unroll
  for (int s = 1; s < 64; s <<= 1) {
    float u = __shfl_down(Bv, s, 64) + 4.0f * (float)s;
    if (lane < 64 - s) Bv = fminf(Bv, u);
  }
  float Be = __shfl_down(Bv, 1, 64);
  if (lane == 63) Be = INF9;

  float v0 = fminf(fminf(lf0, Fe + 1.0f), fminf(lb0, Be + 4.0f));
  float v1 = fminf(fminf(lf1, Fe + 2.0f), fminf(lb1, Be + 3.0f));
  float v2 = fminf(fminf(lf2, Fe + 3.0f), fminf(lb2, Be + 2.0f));
  float v3 = fminf(fminf(lf3, Fe + 4.0f), fminf(lb3, Be + 1.0f));
  v0 = fminf(v0, BIGF); v1 = fminf(v1, BIGF);
  v2 = fminf(v2, BIGF); v3 = fminf(v3, BIGF);
  g2[0] = v0 * v0; g2[1] = v1 * v1; g2[2] = v2 * v2; g2[3] = v3 * v3;
}

__global__ __launch_bounds__(256) void edt_vertical2(
    const float* __restrict__ tgt,
    float* __restrict__ ws) {
  if (blockIdx.x == 0) {
    if (threadIdx.x < 16) ws[P_OFF + threadIdx.x * P_STRIDE] = 0.0f;
    if (threadIdx.x == 16) ((int*)ws)[C_OFF] = 0;
  }

  float* gA2 = ws;
  float* gB2 = ws + NPIX;

  int wid = (blockIdx.x * 256 + threadIdx.x) >> 6;  // column id 0..2047
  int lane = threadIdx.x & 63;
  int b = wid >> 8;
  int w = wid & 255;
  size_t ibase = (size_t)b * HH * WW + w;

  float t0 = tgt[ibase + (size_t)(4 * lane + 0) * WW];
  float t1 = tgt[ibase + (size_t)(4 * lane + 1) * WW];
  float t2 = tgt[ibase + (size_t)(4 * lane + 2) * WW];
  float t3 = tgt[ibase + (size_t)(4 * lane + 3) * WW];
  bool g0 = t0 > 0.5f, g1 = t1 > 0.5f, g2b = t2 > 0.5f, g3 = t3 > 0.5f;

  float a2[4], b2[4];
  col_scan_g2(!g0, !g1, !g2b, !g3, lane, a2);  // A: feature = bg
  col_scan_g2(g0, g1, g2b, g3, lane, b2);      // B: feature = fg

#pragma unroll
  for (int k = 0; k < 4; ++k) {
    size_t o = ibase + (size_t)(4 * lane + k) * WW;
    gA2[o] = a2[k];
    gB2[o] = b2[k];
  }
}

// ---------------------------------------------------------------------------
// Kernel 2: 4 rows per block (1024 threads, 16 waves). Center-out lower
// envelope with wave-uniform early exit:
//   after scanning cols [lo,hi], unscanned j contributes >= b^2 where
//   b = min lane distance to the unscanned boundary; if all lanes have
//   d2 <= b^2 the result is EXACT. Capped at the +-64 window (weight < 5e-6
//   beyond — error far under threshold). Typical wave exits after ~2 rings.
// Reduction: wave shuffle -> LDS -> ONE spread atomicAdd per block;
// last block (atomic counter) sums 16 partials and writes out[0].
// ---------------------------------------------------------------------------
#define ENV_GROUP(kk) { float4 v = s4[kk];                        \
    float D0 = fw - (float)(4 * (kk));                            \
    d2 = fminf(d2, fmaf(D0, D0, v.x));                            \
    float D1 = D0 - 1.0f; d2 = fminf(d2, fmaf(D1, D1, v.y));      \
    float D2 = D0 - 2.0f; d2 = fminf(d2, fmaf(D2, D2, v.z));      \
    float D3 = D0 - 3.0f; d2 = fminf(d2, fmaf(D3, D3, v.w)); }

__global__ __launch_bounds__(1024) void edt_row_loss3(
    const float* __restrict__ pred,
    const float* __restrict__ tgt,
    float* __restrict__ ws,
    float* __restrict__ out) {
  __shared__ __align__(16) float lA[4][WW];
  __shared__ __align__(16) float lB[4][WW];
  __shared__ float wsum[16];
  __shared__ int lastFlag;

  const float* gA2 = ws;
  const float* gB2 = ws + NPIX;
  float* partials = ws + P_OFF;
  int* counter = ((int*)ws) + C_OFF;

  int tid = threadIdx.x;
  size_t base = (size_t)blockIdx.x * (4 * WW);

  ((float*)lA)[tid] = gA2[base + tid];
  ((float*)lB)[tid] = gB2[base + tid];
  float x = pred[base + tid];
  float t = tgt[base + tid];
  __syncthreads();

  int r = tid >> 8;    // row within block
  int w = tid & 255;   // column
  bool fg = t > 0.5f;
  const float4* s4 = (const float4*)(fg ? lA[r] : lB[r]);

  int w0 = w & ~63;          // wave-uniform block base
  int kc0 = w0 >> 2;         // first own j-group
  float fw = (float)w;
  float d2 = 1e30f;

  // own 64-column block: 16 groups (covers |w-j| up to 63 one-sided)
#pragma unroll 4
  for (int k = kc0; k < kc0 + 16; ++k) ENV_GROUP(k);

  // center-out rings with wave-uniform exact early exit
  int kL = kc0 - 1;
  int kR = kc0 + 16;
  for (int iter = 0; iter < 16; ++iter) {
    int bL = (kL >= 0) ? (w0 - 4 * kL - 3) : 100000;   // nearest unscanned left
    int bR = (kR <= 63) ? (4 * kR - w0 - 63) : 100000; // nearest unscanned right
    int bb = min(bL, bR);
    float bb2 = (float)bb * (float)bb;
    if (__all(d2 <= bb2)) break;
    if (kL >= 0) { ENV_GROUP(kL); kL--; }
    if (kR <= 63) { ENV_GROUP(kR); kR++; }
  }

  float dd = sqrtf(d2);
  float weight = 1.0f / (1.0f + __expf((dd - 3.0f) * 0.2f));
  float bce = fmaxf(x, 0.0f) - x * t + log1pf(__expf(-fabsf(x)));
  float c = bce * weight * (1.0f / (float)NPIX);

#pragma unroll
  for (int off = 32; off > 0; off >>= 1) c += __shfl_down(c, off, 64);
  if ((tid & 63) == 0) wsum[tid >> 6] = c;
  __syncthreads();

  if (tid < 64) {
    float v = (tid < 16) ? wsum[tid] : 0.0f;
#pragma unroll
    for (int off = 8; off > 0; off >>= 1) v += __shfl_down(v, off, 64);
    if (tid == 0) {
      atomicAdd(&partials[(blockIdx.x & 15) * P_STRIDE], v);
      __threadfence();
      int done = atomicAdd(counter, 1);
      lastFlag = (done == (int)gridDim.x - 1) ? 1 : 0;
    }
  }
  __syncthreads();

  if (lastFlag && tid < 64) {
    float v = (tid < 16) ? atomicAdd(&partials[tid * P_STRIDE], 0.0f) : 0.0f;
#pragma unroll
    for (int off = 8; off > 0; off >>= 1) v += __shfl_down(v, off, 64);
    if (tid == 0) out[0] = v;
  }
}

extern "C" void kernel_launch(void* const* d_in, const int* in_sizes, int n_in,
                              void* d_out, int out_size, void* d_ws, size_t ws_size,
                              hipStream_t stream) {
  const float* pred = (const float*)d_in[0];
  const float* tgt  = (const float*)d_in[1];
  float* out = (float*)d_out;
  float* ws  = (float*)d_ws;

  edt_vertical2<<<dim3(512), dim3(256), 0, stream>>>(tgt, ws);
  edt_row_loss3<<<dim3(512), dim3(1024), 0, stream>>>(pred, tgt, ws, out);
}